// Round 10
// baseline (232.942 us; speedup 1.0000x reference)
//
#include <hip/hip_runtime.h>
#include <math.h>

#define LSEQ   4096
#define DMODEL 1024
#define NH     16
#define DHEAD  64
#define PSTRIDE 40  // P-buffer row stride in bf16: mult of 8 (b128 align)
// Finite mask: exp2(-30000) == 0 exactly; below-diagonal tiles contribute
// p=0, l=0, O=0 -> trivially correct under the sum-merge (no NaN path).
#define MASKV  -30000.0f
#define C2SCALE 0.18033688f  // 0.125 * log2(e), folded into Q projection

typedef __attribute__((ext_vector_type(8))) short  bf16x8;
typedef __attribute__((ext_vector_type(4))) float  floatx4;
typedef unsigned short ushort_t;

#if __has_builtin(__builtin_amdgcn_exp2f)
#define EXP2F __builtin_amdgcn_exp2f
#else
#define EXP2F exp2f
#endif

__device__ __forceinline__ ushort_t f2bf(float x) {
  unsigned u = __builtin_bit_cast(unsigned, x);
  return (ushort_t)((u + 0x7fff + ((u >> 16) & 1)) >> 16);
}
__device__ __forceinline__ unsigned bf16pair(float a, float b) {
  return (unsigned)f2bf(a) | ((unsigned)f2bf(b) << 16);
}
// truncating pack: low16 = hi16(a), high16 = hi16(b) — 1 VALU (v_perm_b32)
__device__ __forceinline__ unsigned bfpack_trunc(float a, float b) {
  return __builtin_amdgcn_perm(__builtin_bit_cast(unsigned, b),
                               __builtin_bit_cast(unsigned, a), 0x07060302u);
}
__device__ __forceinline__ void gl_lds16(const ushort_t* g, ushort_t* l) {
  __builtin_amdgcn_global_load_lds(
      (const __attribute__((address_space(1))) void*)g,
      (__attribute__((address_space(3))) void*)l, 16, 0, 0);
}

// ---------------------------------------------------------------------------
// Fused prep: blocks [0,8192) = fp32->bf16 for [x|Wq|Wk|Wv|Wo]; blocks
// [8192,8704) = exact f64 RoPE table (rope[s][t] = {cos,sin}(s*invf_t)).
// ---------------------------------------------------------------------------
__global__ void prep_fused(const float* __restrict__ x,  const float* __restrict__ wq,
                           const float* __restrict__ wk, const float* __restrict__ wv,
                           const float* __restrict__ wo, ushort_t* __restrict__ dst,
                           float2* __restrict__ rope) {
  if (blockIdx.x >= 8192) {  // RoPE table: 512 blocks x 256 thr = 131072
    const int idx = (blockIdx.x - 8192) * 256 + threadIdx.x;
    const int s = idx >> 5, t = idx & 31;
    const double invf = exp((double)t * -0.28782313662425572);  // -ln(10000)/32
    const double ang = (double)s * invf;
    rope[idx] = make_float2((float)cos(ang), (float)sin(ang));
    return;
  }
  const size_t e = ((size_t)blockIdx.x * 256 + threadIdx.x) * 4;  // elem idx, 8M total
  const float* src; size_t off;
  if      (e < (size_t)(4u << 20)) { src = x;  off = e; }
  else if (e < (size_t)(5u << 20)) { src = wq; off = e - (size_t)(4u << 20); }
  else if (e < (size_t)(6u << 20)) { src = wk; off = e - (size_t)(5u << 20); }
  else if (e < (size_t)(7u << 20)) { src = wv; off = e - (size_t)(6u << 20); }
  else                             { src = wo; off = e - (size_t)(7u << 20); }
  const float4 v = *(const float4*)(src + off);
  uint2 p; p.x = bf16pair(v.x, v.y); p.y = bf16pair(v.z, v.w);
  *(uint2*)(dst + e) = p;
}

// ---------------------------------------------------------------------------
// 192x256-tile QKV GEMM, R7 pipeline + m201 FINE INTERLEAVE (this round).
// R21 diagnosis: kernel ~50 us (~500 TF) with counted vmcnt but phases still
// issue ds_reads AFTER the phase barrier and MFMA immediately -> full LDS
// first-use latency exposed per phase at 2 waves/SIMD. m196 A/B: the
// per-phase {ds_read issue; stage issue; barrier; lgkmcnt(0); MFMA; barrier}
// interleave IS the 8-phase lever (coarse split without it HURTS -7-27%;
// with it m198->m201 = 1563 TF). This round: each of the 4 phases/K-tile
// becomes the 2-barrier m201 pattern — reads complete during barrier #1's
// wait, lgkmcnt(0)+sched_barrier(0) (rule 18) pins the wait point, setprio'd
// MFMA, barrier #2. Staging quotas and counted vmcnt(3) boundary unchanged:
// A triple-buf dist-2 (issued ph2), B dbuf dist-1 (issued ph0-1); newest 3
// loads ride across the tile boundary (vmcnt never 0 in steady state).
// 8 waves (2M x 4N), per-wave 96x64 = acc[6][4]; 12 MFMA/phase; both-sides
// XOR swizzle; grid 256 = full CU fill; bijective XCD remap.
// ---------------------------------------------------------------------------
__global__ __launch_bounds__(512, 2)
void gemm256_qkv(const ushort_t* __restrict__ A, const ushort_t* __restrict__ B,
                 const float2* __restrict__ rope,
                 ushort_t* __restrict__ Qo, ushort_t* __restrict__ Ko,
                 ushort_t* __restrict__ Vo) {
  // LDS elems: A 3-buf [0, 36864) (3 x 192x64) | B 2-buf [36864, 69632)
  __shared__ __align__(16) ushort_t smem[69632];
  const int tid  = threadIdx.x;
  const int w    = tid >> 6, lane = tid & 63;
  const int wr   = w >> 2,   wc   = w & 3;     // wave -> (M half of 192, N quarter)
  const int quad = lane >> 4, col = lane & 15;
  const int csw  = col & 7;                    // read-side swizzle key
  const int bid = blockIdx.x;
  const int nb  = (bid & 7) * 32 + (bid >> 3);
  const int i0 = (nb & 15) * 192;              // feature rows (Q|K|V)
  const int j0 = (nb >> 4) * 256;              // sequence cols

  const ushort_t* Ab = A + (size_t)i0 * DMODEL;
  const ushort_t* Bb = B + (size_t)j0 * DMODEL;

  const int sr8 = lane >> 3;
  const int sc  = ((lane & 7) ^ sr8) * 8;

  floatx4 acc[6][4];
#pragma unroll
  for (int m = 0; m < 6; ++m)
#pragma unroll
    for (int n = 0; n < 4; ++n) acc[m][n] = (floatx4){0.f, 0.f, 0.f, 0.f};

  auto stageA = [&](int kt, int h) {
    ushort_t* dst = smem + (kt % 3) * 12288 + (h * 64 + w * 8) * 64;
    gl_lds16(Ab + (size_t)(h * 64 + w * 8 + sr8) * DMODEL + kt * 64 + sc, dst);
  };
  auto stageB = [&](int kt, int h) {
    ushort_t* dst = smem + 36864 + (kt & 1) * 16384 + (h * 64 + w * 8) * 64;
    gl_lds16(Bb + (size_t)(h * 64 + w * 8 + sr8) * DMODEL + kt * 64 + sc, dst);
  };

  stageA(0, 0); stageA(0, 1); stageA(0, 2);
  stageB(0, 0); stageB(0, 1); stageB(0, 2); stageB(0, 3);
  stageA(1, 0); stageA(1, 1); stageA(1, 2);
  asm volatile("s_waitcnt vmcnt(3)" ::: "memory");
  __builtin_amdgcn_s_barrier();

  for (int t = 0; t < 16; ++t) {
    const ushort_t* As_ = smem + (t % 3) * 12288;
    const ushort_t* Bs_ = smem + 36864 + (t & 1) * 16384;
    const bool preB = (t + 1 < 16);
    const bool preA = (t + 2 < 16);

    bf16x8 af[3], bfr[4];
    // ---- phase 0: reads(kk=0: bfr, af m0-2) | stage B(t+1) h0-1 | BAR |
    //      lgkm0 | 12 MFMA | BAR ----
#pragma unroll
    for (int n = 0; n < 4; ++n)
      bfr[n] = *(const bf16x8*)(Bs_ + (wc * 64 + n * 16 + col) * 64 + ((quad ^ csw) * 8));
#pragma unroll
    for (int m = 0; m < 3; ++m)
      af[m] = *(const bf16x8*)(As_ + (wr * 96 + m * 16 + col) * 64 + ((quad ^ csw) * 8));
    if (preB) { stageB(t + 1, 0); stageB(t + 1, 1); }
    __builtin_amdgcn_s_barrier();
    asm volatile("s_waitcnt lgkmcnt(0)" ::: "memory");
    __builtin_amdgcn_sched_barrier(0);
    __builtin_amdgcn_s_setprio(1);
#pragma unroll
    for (int m = 0; m < 3; ++m)
#pragma unroll
      for (int n = 0; n < 4; ++n)
        acc[m][n] = __builtin_amdgcn_mfma_f32_16x16x32_bf16(af[m], bfr[n], acc[m][n], 0, 0, 0);
    __builtin_amdgcn_s_setprio(0);
    __builtin_amdgcn_s_barrier();

    // ---- phase 1: reads(af m3-5, bfr reused) | stage B(t+1) h2-3 ----
#pragma unroll
    for (int m = 0; m < 3; ++m)
      af[m] = *(const bf16x8*)(As_ + (wr * 96 + (m + 3) * 16 + col) * 64 + ((quad ^ csw) * 8));
    if (preB) { stageB(t + 1, 2); stageB(t + 1, 3); }
    __builtin_amdgcn_s_barrier();
    asm volatile("s_waitcnt lgkmcnt(0)" ::: "memory");
    __builtin_amdgcn_sched_barrier(0);
    __builtin_amdgcn_s_setprio(1);
#pragma unroll
    for (int m = 0; m < 3; ++m)
#pragma unroll
      for (int n = 0; n < 4; ++n)
        acc[m + 3][n] = __builtin_amdgcn_mfma_f32_16x16x32_bf16(af[m], bfr[n], acc[m + 3][n], 0, 0, 0);
    __builtin_amdgcn_s_setprio(0);
    __builtin_amdgcn_s_barrier();

    // ---- phase 2: reads(kk=1: bfr, af m0-2) | stage A(t+2) all 3 ----
#pragma unroll
    for (int n = 0; n < 4; ++n)
      bfr[n] = *(const bf16x8*)(Bs_ + (wc * 64 + n * 16 + col) * 64 + (((4 + quad) ^ csw) * 8));
#pragma unroll
    for (int m = 0; m < 3; ++m)
      af[m] = *(const bf16x8*)(As_ + (wr * 96 + m * 16 + col) * 64 + (((4 + quad) ^ csw) * 8));
    if (preA) { stageA(t + 2, 0); stageA(t + 2, 1); stageA(t + 2, 2); }
    __builtin_amdgcn_s_barrier();
    asm volatile("s_waitcnt lgkmcnt(0)" ::: "memory");
    __builtin_amdgcn_sched_barrier(0);
    __builtin_amdgcn_s_setprio(1);
#pragma unroll
    for (int m = 0; m < 3; ++m)
#pragma unroll
      for (int n = 0; n < 4; ++n)
        acc[m][n] = __builtin_amdgcn_mfma_f32_16x16x32_bf16(af[m], bfr[n], acc[m][n], 0, 0, 0);
    __builtin_amdgcn_s_setprio(0);
    __builtin_amdgcn_s_barrier();

    // ---- phase 3: reads(af m3-5) | COUNTED vmcnt drain at tile boundary ----
#pragma unroll
    for (int m = 0; m < 3; ++m)
      af[m] = *(const bf16x8*)(As_ + (wr * 96 + (m + 3) * 16 + col) * 64 + (((4 + quad) ^ csw) * 8));
    __builtin_amdgcn_s_barrier();
    asm volatile("s_waitcnt lgkmcnt(0)" ::: "memory");
    __builtin_amdgcn_sched_barrier(0);
    __builtin_amdgcn_s_setprio(1);
#pragma unroll
    for (int m = 0; m < 3; ++m)
#pragma unroll
      for (int n = 0; n < 4; ++n)
        acc[m + 3][n] = __builtin_amdgcn_mfma_f32_16x16x32_bf16(af[m], bfr[n], acc[m + 3][n], 0, 0, 0);
    __builtin_amdgcn_s_setprio(0);
    if (preA) asm volatile("s_waitcnt vmcnt(3)" ::: "memory");
    else      asm volatile("s_waitcnt vmcnt(0)" ::: "memory");
    __builtin_amdgcn_s_barrier();
  }

  // ---- epilogue: which/h/d per fragment (tiles straddle Q/K/V bounds) ----
#pragma unroll
  for (int m = 0; m < 6; ++m) {
    const int f0    = i0 + wr * 96 + m * 16 + quad * 4;
    const int which = f0 >> 10;               // 0=Q 1=K 2=V
    const int h     = (f0 >> 6) & 15;
    const int d     = f0 & 63;
    if (which == 2) {
#pragma unroll
      for (int n = 0; n < 4; ++n) {
        const int s = j0 + wc * 64 + n * 16 + col;
#pragma unroll
        for (int r = 0; r < 4; ++r)
          Vo[(size_t)(h * DHEAD + d + r) * LSEQ + s] = f2bf(acc[m][n][r]);
      }
    } else {
      ushort_t* dst = which ? Ko : Qo;
      const float qs = which ? 1.0f : C2SCALE;  // fold softmax scale into Q
      const int t0 = d >> 1;
#pragma unroll
      for (int n = 0; n < 4; ++n) {
        const int s = j0 + wc * 64 + n * 16 + col;
        const float4 cst = *(const float4*)((const float*)rope + ((size_t)s << 6) + t0 * 2);
        ushort_t* ob = dst + ((size_t)h * LSEQ + s) * DHEAD;
        const float x1 = acc[m][n][0], x2 = acc[m][n][1];
        const float y1 = acc[m][n][2], y2 = acc[m][n][3];
        *(unsigned*)(ob + t0)      = bf16pair((x1 * cst.x - x2 * cst.y) * qs,
                                              (y1 * cst.z - y2 * cst.w) * qs);
        *(unsigned*)(ob + t0 + 32) = bf16pair((x1 * cst.y + x2 * cst.x) * qs,
                                              (y1 * cst.w + y2 * cst.z) * qs);
      }
    }
  }
}

// ---------------------------------------------------------------------------
// m97-style bf16 MFMA GEMM + XOR-swizzled LDS + XCD swizzle. MODE 0 (final
// projection): A=Om(bf16), B=Wo(bf16) -> fp32 C row-major. Unchanged.
// ---------------------------------------------------------------------------
template<int MODE>
__global__ __launch_bounds__(256)
void mfma_gemm(const ushort_t* __restrict__ A, const ushort_t* __restrict__ B,
               float* __restrict__ C, const float2* __restrict__ rope,
               ushort_t* __restrict__ Qo, ushort_t* __restrict__ Ko,
               ushort_t* __restrict__ Vo) {
  __shared__ ushort_t As[128 * 64];
  __shared__ ushort_t Bs[128 * 64];
  const int tid  = threadIdx.x;
  const int w    = tid >> 6, lane = tid & 63;
  const int wm   = w >> 1,   wn   = w & 1;
  const int quad = lane >> 4, col = lane & 15;
  const int csw  = col & 7;
  const int bid = blockIdx.y * 32 + blockIdx.x;
  const int nb  = (bid & 7) * 32 + (bid >> 3);
  const int i0 = (nb % 32) * 128;
  const int j0 = (nb / 32) * 128;

  const ushort_t* Ab = A + (size_t)i0 * DMODEL;
  const ushort_t* Bb = B + (size_t)j0 * DMODEL;

  floatx4 acc[4][4];
#pragma unroll
  for (int mt = 0; mt < 4; ++mt)
#pragma unroll
    for (int nt = 0; nt < 4; ++nt) acc[mt][nt] = (floatx4){0.f, 0.f, 0.f, 0.f};

  const int lrow = lane >> 3;
  const int lcol = ((lane & 7) ^ lrow) * 8;

  for (int k0 = 0; k0 < DMODEL; k0 += 64) {
    __syncthreads();
#pragma unroll
    for (int it = 0; it < 4; ++it) {
      const int rb = (it * 4 + w) * 8;
      gl_lds16(Ab + (size_t)(rb + lrow) * DMODEL + k0 + lcol, As + rb * 64);
      gl_lds16(Bb + (size_t)(rb + lrow) * DMODEL + k0 + lcol, Bs + rb * 64);
    }
    __syncthreads();

#pragma unroll
    for (int kk = 0; kk < 64; kk += 32) {
      const int cblk = (kk >> 3) + quad;
      bf16x8 af[4], bfr[4];
#pragma unroll
      for (int mt = 0; mt < 4; ++mt)
        af[mt] = *(const bf16x8*)(As + (wm * 64 + mt * 16 + col) * 64 +
                                  ((cblk ^ csw) * 8));
#pragma unroll
      for (int nt = 0; nt < 4; ++nt)
        bfr[nt] = *(const bf16x8*)(Bs + (wn * 64 + nt * 16 + col) * 64 +
                                   ((cblk ^ csw) * 8));
#pragma unroll
      for (int mt = 0; mt < 4; ++mt)
#pragma unroll
        for (int nt = 0; nt < 4; ++nt)
          acc[mt][nt] = __builtin_amdgcn_mfma_f32_16x16x32_bf16(
              af[mt], bfr[nt], acc[mt][nt], 0, 0, 0);
    }
  }

  if (MODE == 0) {
#pragma unroll
    for (int mt = 0; mt < 4; ++mt) {
      const int i = i0 + wm * 64 + mt * 16 + quad * 4;
#pragma unroll
      for (int nt = 0; nt < 4; ++nt) {
        const int j = j0 + wn * 64 + nt * 16 + col;
#pragma unroll
        for (int r = 0; r < 4; ++r)
          C[(size_t)(i + r) * DMODEL + j] = acc[mt][nt][r];
      }
    }
  } else {
    const int which = i0 >> 10;
#pragma unroll
    for (int mt = 0; mt < 4; ++mt) {
      const int f0 = i0 + wm * 64 + mt * 16 + quad * 4;
      const int h  = (f0 >> 6) & 15;
      const int d  = f0 & 63;
      if (which == 2) {
#pragma unroll
        for (int nt = 0; nt < 4; ++nt) {
          const int s = j0 + wn * 64 + nt * 16 + col;
#pragma unroll
          for (int r = 0; r < 4; ++r)
            Vo[(size_t)(h * DHEAD + d + r) * LSEQ + s] = f2bf(acc[mt][nt][r]);
        }
      } else {
        ushort_t* dst = which ? Ko : Qo;
        const float qs = which ? 1.0f : C2SCALE;
        const int t0 = d >> 1;
#pragma unroll
        for (int nt = 0; nt < 4; ++nt) {
          const int s = j0 + wn * 64 + nt * 16 + col;
          const float4 cst = *(const float4*)((const float*)rope + ((size_t)s << 6) + t0 * 2);
          ushort_t* ob = dst + ((size_t)h * LSEQ + s) * DHEAD;
          const float x1 = acc[mt][nt][0], x2 = acc[mt][nt][1];
          const float y1 = acc[mt][nt][2], y2 = acc[mt][nt][3];
          *(unsigned*)(ob + t0)      = bf16pair((x1 * cst.x - x2 * cst.y) * qs,
                                                (y1 * cst.z - y2 * cst.w) * qs);
          *(unsigned*)(ob + t0 + 32) = bf16pair((x1 * cst.y + x2 * cst.x) * qs,
                                                (y1 * cst.w + y2 * cst.z) * qs);
        }
      }
    }
  }
}

// ---------------------------------------------------------------------------
// MFMA flash attention v12 + T5 setprio (best measured: 59.0 us). Unchanged.
// 3 LDS buffers per parity group, prefetch distance 2, counted vmcnt(2) +
// raw s_barrier per tile. 1024 thr, 16 waves = 4 q-units x 2 key-halves x
// 2 kt-parity groups. LDS 136 KiB; Obuf aliases staging.
// ---------------------------------------------------------------------------
__global__ __launch_bounds__(1024, 4)
void attn_mfma(const ushort_t* __restrict__ Qh, const ushort_t* __restrict__ Kh,
               const ushort_t* __restrict__ Vt, ushort_t* __restrict__ Om) {
  const int h   = blockIdx.x;
  const int g   = blockIdx.y;    // 0..15
  const int tid = threadIdx.x;
  const int w     = tid >> 6;      // 0..15
  const int wl    = w & 3;         // q-unit slot (32 q rows each)
  const int half  = (w >> 2) & 1;  // keys [0,32) or [32,64) of each tile
  const int ktpar = w >> 3;        // 0 = even tiles, 1 = odd tiles
  const int wg    = w & 7;         // staging wave index within parity group
  const int lane = tid & 63;
  const int quad = lane >> 4;
  const int col  = lane & 15;
  const int csw  = col & 7;      // row-derived swizzle key for reads

  __shared__ __align__(16) char smem[139264];
  ushort_t* Ks   = (ushort_t*)smem;                  // [6][64*64], swizzled
  ushort_t* Vs   = (ushort_t*)(smem + 49152);        // [6][64*64], swizzled
  ushort_t* Ps   = (ushort_t*)(smem + 98304);        // [16][32*PSTRIDE]
  float*    Obuf = (float*)smem;
  __shared__ float lbuf[3][4][2][16];
  ushort_t* psw = Ps + w * (32 * PSTRIDE);

  const int srow = wg * 8 + (lane >> 3);
  const int scol = (((lane & 7) ^ ((lane >> 3) & 7)) * 8);

  for (int pass = 0; pass < 2; ++pass) {
    const int qb      = pass ? (31 - g) : g;
    const int qbase   = qb * 128 + wl * 32;
    const int nkt_max = 2 * qb + 2;   // uniform across all waves, always even
    const int nt2     = nkt_max >> 1; // tiles per parity group

    // Q B-frags (pre-scaled by C2), resident for the key loop
    bf16x8 qf[2][2];
#pragma unroll
    for (int nq = 0; nq < 2; ++nq)
#pragma unroll
      for (int c = 0; c < 2; ++c)
        qf[nq][c] = *(const bf16x8*)(Qh +
            ((size_t)(h * LSEQ + qbase + nq * 16 + col)) * DHEAD + quad * 8 + c * 32);

    floatx4 ot[4][2];
#pragma unroll
    for (int md = 0; md < 4; ++md)
#pragma unroll
      for (int nq = 0; nq < 2; ++nq) ot[md][nq] = (floatx4){0.f, 0.f, 0.f, 0.f};
    float l_[2] = {0.f, 0.f};

    // stage tile kt into this parity group's LDS buffer b (0..2)
    auto stage = [&](int kt, int b) {
      const int key0 = kt * 64;
      const int boff = (ktpar * 3 + b) * 4096;
      gl_lds16(Kh + ((size_t)(h * LSEQ + key0 + srow)) * DHEAD + scol,
               Ks + boff + wg * 512);
      gl_lds16(Vt + ((size_t)(h * DHEAD + srow)) * LSEQ + key0 + scol,
               Vs + boff + wg * 512);
    };

    // prologue: stage iterations 0 and (if any) 1; wait only for iter 0
    stage(ktpar, 0);
    if (nt2 > 1) {
      stage(ktpar + 2, 1);
      asm volatile("s_waitcnt vmcnt(2)" ::: "memory");
    } else {
      asm volatile("s_waitcnt vmcnt(0)" ::: "memory");
    }
    __builtin_amdgcn_s_barrier();
    asm volatile("" ::: "memory");

    int bufn = 0;  // = ktt % 3
    for (int ktt = 0; ktt < nt2; ++ktt) {
      const int kt  = 2 * ktt + ktpar;
      const bool pre = (ktt + 2 < nt2);
      if (pre) {
        const int nb = (bufn >= 1) ? bufn - 1 : 2;  // (ktt+2) % 3
        stage(kt + 4, nb);
      }

      const ushort_t* kb = Ks + (ktpar * 3 + bufn) * 4096;
      const ushort_t* vb = Vs + (ktpar * 3 + bufn) * 4096;

      // kf frags from LDS (swizzled): row rk = half*32+mk*16+col, rk&7 = csw
      bf16x8 kf[2][2];
#pragma unroll
      for (int mk = 0; mk < 2; ++mk)
#pragma unroll
        for (int c = 0; c < 2; ++c)
          kf[mk][c] = *(const bf16x8*)(kb + (half * 32 + mk * 16 + col) * 64 +
                                       (((c * 4 + quad) ^ csw) * 8));

      // S^T = K . (C2*Q)^T  (32 keys x 32 q)
      floatx4 st[2][2];
#pragma unroll
      for (int mk = 0; mk < 2; ++mk)
#pragma unroll
        for (int nq = 0; nq < 2; ++nq) st[mk][nq] = (floatx4){0.f, 0.f, 0.f, 0.f};
      __builtin_amdgcn_s_setprio(1);
#pragma unroll
      for (int mk = 0; mk < 2; ++mk)
#pragma unroll
        for (int c = 0; c < 2; ++c)
#pragma unroll
          for (int nq = 0; nq < 2; ++nq)
            st[mk][nq] = __builtin_amdgcn_mfma_f32_16x16x32_bf16(
                kf[mk][c], qf[nq][c], st[mk][nq], 0, 0, 0);
      __builtin_amdgcn_s_setprio(0);

      // mask near/beyond the diagonal
      if (kt >= nkt_max - 2) {
        const int key0 = kt * 64 + half * 32;
#pragma unroll
        for (int mk = 0; mk < 2; ++mk) {
          const int keyb = key0 + mk * 16 + quad * 4;
#pragma unroll
          for (int nq = 0; nq < 2; ++nq) {
            const int q = qbase + nq * 16 + col;
#pragma unroll
            for (int r = 0; r < 4; ++r)
              if (keyb + r > q) st[mk][nq][r] = MASKV;
          }
        }
      }

      // p = exp2(S); accumulate l per-lane
#pragma unroll
      for (int mk = 0; mk < 2; ++mk)
#pragma unroll
        for (int nq = 0; nq < 2; ++nq) {
#pragma unroll
          for (int r = 0; r < 4; ++r) st[mk][nq][r] = EXP2F(st[mk][nq][r]);
          l_[nq] += (st[mk][nq][0] + st[mk][nq][1]) + (st[mk][nq][2] + st[mk][nq][3]);
        }

      // P^T -> per-wave LDS (truncating pack), then P B-frags
#pragma unroll
      for (int mk = 0; mk < 2; ++mk)
#pragma unroll
        for (int nq = 0; nq < 2; ++nq) {
          uint2 pk;
          pk.x = bfpack_trunc(st[mk][nq][0], st[mk][nq][1]);
          pk.y = bfpack_trunc(st[mk][nq][2], st[mk][nq][3]);
          *(uint2*)(psw + (nq * 16 + col) * PSTRIDE + mk * 16 + quad * 4) = pk;
        }
      bf16x8 pf[2];
#pragma unroll
      for (int nq = 0; nq < 2; ++nq)
        pf[nq] = *(const bf16x8*)(psw + (nq * 16 + col) * PSTRIDE + quad * 8);

      // vf frags from LDS (swizzled): row rv = md*16+col, rv&7 = csw
      bf16x8 vf[4];
#pragma unroll
      for (int md = 0; md < 4; ++md)
        vf[md] = *(const bf16x8*)(vb + (md * 16 + col) * 64 +
                                  (((half * 4 + quad) ^ csw) * 8));
      __builtin_amdgcn_s_setprio(1);
#pragma unroll
      for (int md = 0; md < 4; ++md)
#pragma unroll
        for (int nq = 0; nq < 2; ++nq)
          ot[md][nq] = __builtin_amdgcn_mfma_f32_16x16x32_bf16(
              vf[md], pf[nq], ot[md][nq], 0, 0, 0);
      __builtin_amdgcn_s_setprio(0);

      // counted wait: drain everything except the stage just issued
      if (pre) asm volatile("s_waitcnt vmcnt(2)" ::: "memory");
      else     asm volatile("s_waitcnt vmcnt(0)" ::: "memory");
      __builtin_amdgcn_s_barrier();
      asm volatile("" ::: "memory");
      bufn = (bufn == 2) ? 0 : bufn + 1;
    }

    // one-time l reduction per pass
    float lr[2];
#pragma unroll
    for (int nq = 0; nq < 2; ++nq) {
      float ls = l_[nq];
      ls += __shfl_xor(ls, 16);
      ls += __shfl_xor(ls, 32);
      lr[nq] = ls;
    }

    // 3 non-merger groups dump partials (Obuf aliases staging); merger is
    // group (half=0, ktpar=0).
    const int di = ((half << 1) | ktpar) - 1;  // -1 merger, else 0..2
    if (di >= 0) {
#pragma unroll
      for (int nq = 0; nq < 2; ++nq) {
        if (quad == 0) lbuf[di][wl][nq][col] = lr[nq];
#pragma unroll
        for (int md = 0; md < 4; ++md)
          *(float4*)(Obuf + di * 8704 + ((wl * 2 + nq) * 16 + col) * 68 + md * 16 + quad * 4) =
              (float4){ot[md][nq][0], ot[md][nq][1], ot[md][nq][2], ot[md][nq][3]};
      }
    }
    __syncthreads();

    if (di < 0) {  // merger group sums 4 partials and writes Om
#pragma unroll
      for (int nq = 0; nq < 2; ++nq) {
        const float inv = 1.0f / (lr[nq] + lbuf[0][wl][nq][col] +
                                  lbuf[1][wl][nq][col] + lbuf[2][wl][nq][col]);
        const int q = qbase + nq * 16 + col;
#pragma unroll
        for (int md = 0; md < 4; ++md) {
          const int ob_off = ((wl * 2 + nq) * 16 + col) * 68 + md * 16 + quad * 4;
          const float4 o0 = *(const float4*)(Obuf + ob_off);
          const float4 o1 = *(const float4*)(Obuf + 8704 + ob_off);
          const float4 o2 = *(const float4*)(Obuf + 17408 + ob_off);
          uint2 pk;
          pk.x = bf16pair((ot[md][nq][0] + o0.x + o1.x + o2.x) * inv,
                          (ot[md][nq][1] + o0.y + o1.y + o2.y) * inv);
          pk.y = bf16pair((ot[md][nq][2] + o0.z + o1.z + o2.z) * inv,
                          (ot[md][nq][3] + o0.w + o1.w + o2.w) * inv);
          *(uint2*)(Om + (size_t)q * DMODEL + h * DHEAD + md * 16 + quad * 4) = pk;
        }
      }
    }
    __syncthreads();  // Obuf reads done before next pass re-stages over it
  }
}

extern "C" void kernel_launch(void* const* d_in, const int* in_sizes, int n_in,
                              void* d_out, int out_size, void* d_ws, size_t ws_size,
                              hipStream_t stream) {
  const float* x  = (const float*)d_in[0];
  const float* Wq = (const float*)d_in[2];
  const float* Wk = (const float*)d_in[3];
  const float* Wv = (const float*)d_in[4];
  const float* Wo = (const float*)d_in[5];
  float* out = (float*)d_out;

  const size_t M1 = (size_t)1 << 20;
  ushort_t* xb  = (ushort_t*)d_ws;      // bf16 x          4M elems
  ushort_t* Wb  = xb  + 4 * M1;         // bf16 Wq|Wk|Wv   3M (contiguous)
  ushort_t* wob = Wb  + 3 * M1;         // bf16 Wo         1M
  ushort_t* Qh  = wob + 1 * M1;         // bf16 [H][L][DH] 4M (pre-scaled C2)
  ushort_t* Kh  = Qh  + 4 * M1;         // bf16 [H][L][DH] 4M
  ushort_t* Vt  = Kh  + 4 * M1;         // bf16 [H][DH][L] 4M
  ushort_t* Om  = Vt  + 4 * M1;         // bf16 [L][D]     4M
  float2*   rope = (float2*)(Om + 4 * M1);  // 4096x32 float2, 1 MB

  prep_fused<<<8704, 256, 0, stream>>>(x, Wq, Wk, Wv, Wo, xb, rope);
  gemm256_qkv<<<256, 512, 0, stream>>>(Wb, xb, rope, Qh, Kh, Vt);
  attn_mfma<<<dim3(NH, 16), 1024, 0, stream>>>(Qh, Kh, Vt, Om);
  mfma_gemm<0><<<dim3(32, 8), 256, 0, stream>>>(
      Om, wob, out, nullptr, nullptr, nullptr, nullptr);
}

// Round 11
// 224.275 us; speedup vs baseline: 1.0386x; 1.0386x over previous
//
#include <hip/hip_runtime.h>
#include <math.h>

#define LSEQ   4096
#define DMODEL 1024
#define NH     16
#define DHEAD  64
#define PSTRIDE 40  // P-buffer row stride in bf16: mult of 8 (b128 align)
// Finite mask: exp2(-30000) == 0 exactly; below-diagonal tiles contribute
// p=0, l=0, O=0 -> trivially correct under the sum-merge (no NaN path).
#define MASKV  -30000.0f
#define C2SCALE 0.18033688f  // 0.125 * log2(e), folded into Q projection

typedef __attribute__((ext_vector_type(8))) short  bf16x8;
typedef __attribute__((ext_vector_type(4))) float  floatx4;
typedef unsigned short ushort_t;

#if __has_builtin(__builtin_amdgcn_exp2f)
#define EXP2F __builtin_amdgcn_exp2f
#else
#define EXP2F exp2f
#endif

__device__ __forceinline__ ushort_t f2bf(float x) {
  unsigned u = __builtin_bit_cast(unsigned, x);
  return (ushort_t)((u + 0x7fff + ((u >> 16) & 1)) >> 16);
}
__device__ __forceinline__ unsigned bf16pair(float a, float b) {
  return (unsigned)f2bf(a) | ((unsigned)f2bf(b) << 16);
}
// truncating pack: low16 = hi16(a), high16 = hi16(b) — 1 VALU (v_perm_b32)
__device__ __forceinline__ unsigned bfpack_trunc(float a, float b) {
  return __builtin_amdgcn_perm(__builtin_bit_cast(unsigned, b),
                               __builtin_bit_cast(unsigned, a), 0x07060302u);
}
__device__ __forceinline__ void gl_lds16(const ushort_t* g, ushort_t* l) {
  __builtin_amdgcn_global_load_lds(
      (const __attribute__((address_space(1))) void*)g,
      (__attribute__((address_space(3))) void*)l, 16, 0, 0);
}

// ---------------------------------------------------------------------------
// Fused prep: blocks [0,8192) = fp32->bf16 for [x|Wq|Wk|Wv|Wo]; blocks
// [8192,8704) = exact f64 RoPE table (rope[s][t] = {cos,sin}(s*invf_t)).
// ---------------------------------------------------------------------------
__global__ void prep_fused(const float* __restrict__ x,  const float* __restrict__ wq,
                           const float* __restrict__ wk, const float* __restrict__ wv,
                           const float* __restrict__ wo, ushort_t* __restrict__ dst,
                           float2* __restrict__ rope) {
  if (blockIdx.x >= 8192) {  // RoPE table: 512 blocks x 256 thr = 131072
    const int idx = (blockIdx.x - 8192) * 256 + threadIdx.x;
    const int s = idx >> 5, t = idx & 31;
    const double invf = exp((double)t * -0.28782313662425572);  // -ln(10000)/32
    const double ang = (double)s * invf;
    rope[idx] = make_float2((float)cos(ang), (float)sin(ang));
    return;
  }
  const size_t e = ((size_t)blockIdx.x * 256 + threadIdx.x) * 4;  // elem idx, 8M total
  const float* src; size_t off;
  if      (e < (size_t)(4u << 20)) { src = x;  off = e; }
  else if (e < (size_t)(5u << 20)) { src = wq; off = e - (size_t)(4u << 20); }
  else if (e < (size_t)(6u << 20)) { src = wk; off = e - (size_t)(5u << 20); }
  else if (e < (size_t)(7u << 20)) { src = wv; off = e - (size_t)(6u << 20); }
  else                             { src = wo; off = e - (size_t)(7u << 20); }
  const float4 v = *(const float4*)(src + off);
  uint2 p; p.x = bf16pair(v.x, v.y); p.y = bf16pair(v.z, v.w);
  *(uint2*)(dst + e) = p;
}

// ---------------------------------------------------------------------------
// 192x256-tile QKV GEMM with counted-vmcnt pipeline (R7 version, reverted:
// R10's per-phase fine interleave was neutral within noise — the simpler
// body is kept to minimize co-compile codegen perturbation, rule #19).
// A triple-buf dist-2, B dbuf dist-1, vmcnt(3) boundary (never 0 in steady
// state). 8 waves (2M x 4N); both-sides XOR swizzle; 256-block full fill;
// bijective XCD remap. RoPE / V^T epilogues.
// ---------------------------------------------------------------------------
__global__ __launch_bounds__(512, 2)
void gemm256_qkv(const ushort_t* __restrict__ A, const ushort_t* __restrict__ B,
                 const float2* __restrict__ rope,
                 ushort_t* __restrict__ Qo, ushort_t* __restrict__ Ko,
                 ushort_t* __restrict__ Vo) {
  // LDS elems: A 3-buf [0, 36864) (3 x 192x64) | B 2-buf [36864, 69632)
  __shared__ __align__(16) ushort_t smem[69632];
  const int tid  = threadIdx.x;
  const int w    = tid >> 6, lane = tid & 63;
  const int wr   = w >> 2,   wc   = w & 3;     // wave -> (M half of 192, N quarter)
  const int quad = lane >> 4, col = lane & 15;
  const int csw  = col & 7;                    // read-side swizzle key
  const int bid = blockIdx.x;
  const int nb  = (bid & 7) * 32 + (bid >> 3);
  const int i0 = (nb & 15) * 192;              // feature rows (Q|K|V)
  const int j0 = (nb >> 4) * 256;              // sequence cols

  const ushort_t* Ab = A + (size_t)i0 * DMODEL;
  const ushort_t* Bb = B + (size_t)j0 * DMODEL;

  const int sr8 = lane >> 3;
  const int sc  = ((lane & 7) ^ sr8) * 8;

  floatx4 acc[6][4];
#pragma unroll
  for (int m = 0; m < 6; ++m)
#pragma unroll
    for (int n = 0; n < 4; ++n) acc[m][n] = (floatx4){0.f, 0.f, 0.f, 0.f};

  auto stageA = [&](int kt, int h) {
    ushort_t* dst = smem + (kt % 3) * 12288 + (h * 64 + w * 8) * 64;
    gl_lds16(Ab + (size_t)(h * 64 + w * 8 + sr8) * DMODEL + kt * 64 + sc, dst);
  };
  auto stageB = [&](int kt, int h) {
    ushort_t* dst = smem + 36864 + (kt & 1) * 16384 + (h * 64 + w * 8) * 64;
    gl_lds16(Bb + (size_t)(h * 64 + w * 8 + sr8) * DMODEL + kt * 64 + sc, dst);
  };

  stageA(0, 0); stageA(0, 1); stageA(0, 2);
  stageB(0, 0); stageB(0, 1); stageB(0, 2); stageB(0, 3);
  stageA(1, 0); stageA(1, 1); stageA(1, 2);
  asm volatile("s_waitcnt vmcnt(3)" ::: "memory");
  __builtin_amdgcn_s_barrier();

  for (int t = 0; t < 16; ++t) {
    const ushort_t* As_ = smem + (t % 3) * 12288;
    const ushort_t* Bs_ = smem + 36864 + (t & 1) * 16384;
    const bool preB = (t + 1 < 16);
    const bool preA = (t + 2 < 16);

    bf16x8 af[3], bfr[4];
    // ---- phase 0: kk=0, m 0..2 ----
#pragma unroll
    for (int n = 0; n < 4; ++n)
      bfr[n] = *(const bf16x8*)(Bs_ + (wc * 64 + n * 16 + col) * 64 + ((quad ^ csw) * 8));
#pragma unroll
    for (int m = 0; m < 3; ++m)
      af[m] = *(const bf16x8*)(As_ + (wr * 96 + m * 16 + col) * 64 + ((quad ^ csw) * 8));
    if (preB) { stageB(t + 1, 0); stageB(t + 1, 1); }
    __builtin_amdgcn_s_setprio(1);
#pragma unroll
    for (int m = 0; m < 3; ++m)
#pragma unroll
      for (int n = 0; n < 4; ++n)
        acc[m][n] = __builtin_amdgcn_mfma_f32_16x16x32_bf16(af[m], bfr[n], acc[m][n], 0, 0, 0);
    __builtin_amdgcn_s_setprio(0);
    __builtin_amdgcn_s_barrier();

    // ---- phase 1: kk=0, m 3..5 (bfr reused) ----
#pragma unroll
    for (int m = 0; m < 3; ++m)
      af[m] = *(const bf16x8*)(As_ + (wr * 96 + (m + 3) * 16 + col) * 64 + ((quad ^ csw) * 8));
    if (preB) { stageB(t + 1, 2); stageB(t + 1, 3); }
    __builtin_amdgcn_s_setprio(1);
#pragma unroll
    for (int m = 0; m < 3; ++m)
#pragma unroll
      for (int n = 0; n < 4; ++n)
        acc[m + 3][n] = __builtin_amdgcn_mfma_f32_16x16x32_bf16(af[m], bfr[n], acc[m + 3][n], 0, 0, 0);
    __builtin_amdgcn_s_setprio(0);
    __builtin_amdgcn_s_barrier();

    // ---- phase 2: kk=1, m 0..2; issue A(t+2) (deep prefetch) ----
#pragma unroll
    for (int n = 0; n < 4; ++n)
      bfr[n] = *(const bf16x8*)(Bs_ + (wc * 64 + n * 16 + col) * 64 + (((4 + quad) ^ csw) * 8));
#pragma unroll
    for (int m = 0; m < 3; ++m)
      af[m] = *(const bf16x8*)(As_ + (wr * 96 + m * 16 + col) * 64 + (((4 + quad) ^ csw) * 8));
    if (preA) { stageA(t + 2, 0); stageA(t + 2, 1); stageA(t + 2, 2); }
    __builtin_amdgcn_s_setprio(1);
#pragma unroll
    for (int m = 0; m < 3; ++m)
#pragma unroll
      for (int n = 0; n < 4; ++n)
        acc[m][n] = __builtin_amdgcn_mfma_f32_16x16x32_bf16(af[m], bfr[n], acc[m][n], 0, 0, 0);
    __builtin_amdgcn_s_setprio(0);
    __builtin_amdgcn_s_barrier();

    // ---- phase 3: kk=1, m 3..5, then COUNTED drain ----
#pragma unroll
    for (int m = 0; m < 3; ++m)
      af[m] = *(const bf16x8*)(As_ + (wr * 96 + (m + 3) * 16 + col) * 64 + (((4 + quad) ^ csw) * 8));
    __builtin_amdgcn_s_setprio(1);
#pragma unroll
    for (int m = 0; m < 3; ++m)
#pragma unroll
      for (int n = 0; n < 4; ++n)
        acc[m + 3][n] = __builtin_amdgcn_mfma_f32_16x16x32_bf16(af[m], bfr[n], acc[m + 3][n], 0, 0, 0);
    __builtin_amdgcn_s_setprio(0);
    if (preA) asm volatile("s_waitcnt vmcnt(3)" ::: "memory");
    else      asm volatile("s_waitcnt vmcnt(0)" ::: "memory");
    __builtin_amdgcn_s_barrier();
  }

  // ---- epilogue: which/h/d per fragment (tiles straddle Q/K/V bounds) ----
#pragma unroll
  for (int m = 0; m < 6; ++m) {
    const int f0    = i0 + wr * 96 + m * 16 + quad * 4;
    const int which = f0 >> 10;               // 0=Q 1=K 2=V
    const int h     = (f0 >> 6) & 15;
    const int d     = f0 & 63;
    if (which == 2) {
#pragma unroll
      for (int n = 0; n < 4; ++n) {
        const int s = j0 + wc * 64 + n * 16 + col;
#pragma unroll
        for (int r = 0; r < 4; ++r)
          Vo[(size_t)(h * DHEAD + d + r) * LSEQ + s] = f2bf(acc[m][n][r]);
      }
    } else {
      ushort_t* dst = which ? Ko : Qo;
      const float qs = which ? 1.0f : C2SCALE;  // fold softmax scale into Q
      const int t0 = d >> 1;
#pragma unroll
      for (int n = 0; n < 4; ++n) {
        const int s = j0 + wc * 64 + n * 16 + col;
        const float4 cst = *(const float4*)((const float*)rope + ((size_t)s << 6) + t0 * 2);
        ushort_t* ob = dst + ((size_t)h * LSEQ + s) * DHEAD;
        const float x1 = acc[m][n][0], x2 = acc[m][n][1];
        const float y1 = acc[m][n][2], y2 = acc[m][n][3];
        *(unsigned*)(ob + t0)      = bf16pair((x1 * cst.x - x2 * cst.y) * qs,
                                              (y1 * cst.z - y2 * cst.w) * qs);
        *(unsigned*)(ob + t0 + 32) = bf16pair((x1 * cst.y + x2 * cst.x) * qs,
                                              (y1 * cst.w + y2 * cst.z) * qs);
      }
    }
  }
}

// ---------------------------------------------------------------------------
// Final projection GEMM v2 (this round's change): A=Om(bf16) [4096x1024],
// B=Wo(bf16) [1024x1024] -> fp32 out, 128x128 tiles.
// R22 diagnosis: old gemm0 ran 256 blocks x 256 thr = 4 waves/CU = 1
// wave/SIMD (lowest occupancy in the pipeline; ~390 TF) with two full
// vmcnt(0)+lgkmcnt(0) drains per K-step. Grid is fixed at 256 (32x8 tiles),
// so double the BLOCK: 512 thr / 8 waves on the same 128^2 tile (2
// waves/SIMD), and adopt the proven attn-v12 pipeline: A+B TRIPLE-buffered
// (96 KB), prefetch distance 2, counted s_waitcnt vmcnt(4) + raw s_barrier
// per K-tile — the newest 4 loads (tile t+2) ride across the barrier; 0
// only in the 2-tile tail. Per-wave out 32x64 = acc[2][4]; 16 MFMA/tile.
// Both-sides XOR swizzle; bijective XCD remap (each XCD owns one j-panel of
// Wo = 256 KB, L2-resident). K accumulation order unchanged -> bit-identical.
// ---------------------------------------------------------------------------
__global__ __launch_bounds__(512, 2)
void gemm_out(const ushort_t* __restrict__ A, const ushort_t* __restrict__ B,
              float* __restrict__ C) {
  // LDS elems: A 3-buf [0,24576) (3 x 128x64) | B 3-buf [24576,49152)
  __shared__ __align__(16) ushort_t smem[49152];
  const int tid  = threadIdx.x;
  const int w    = tid >> 6, lane = tid & 63;
  const int wm   = w >> 1,   wn   = w & 1;     // wave -> (M quarter, N half)
  const int quad = lane >> 4, col = lane & 15;
  const int csw  = col & 7;                    // read-side swizzle key
  // bijective XCD remap: 256 blocks = 8 XCD x 32; XCD x owns j-panel x
  const int bid = blockIdx.x;
  const int nb  = (bid & 7) * 32 + (bid >> 3);
  const int i0 = (nb & 31) * 128;              // Om rows
  const int j0 = (nb >> 5) * 128;              // out cols (Wo rows)

  const ushort_t* Ab = A + (size_t)i0 * DMODEL;
  const ushort_t* Bb = B + (size_t)j0 * DMODEL;

  const int sr8 = lane >> 3;
  const int sc  = ((lane & 7) ^ sr8) * 8;

  floatx4 acc[2][4];
#pragma unroll
  for (int m = 0; m < 2; ++m)
#pragma unroll
    for (int n = 0; n < 4; ++n) acc[m][n] = (floatx4){0.f, 0.f, 0.f, 0.f};

  // stage 64-row chunk h (0/1) of A/B K-tile kt into buffer kt%3
  auto stageA = [&](int kt, int h) {
    ushort_t* dst = smem + (kt % 3) * 8192 + (h * 64 + w * 8) * 64;
    gl_lds16(Ab + (size_t)(h * 64 + w * 8 + sr8) * DMODEL + kt * 64 + sc, dst);
  };
  auto stageB = [&](int kt, int h) {
    ushort_t* dst = smem + 24576 + (kt % 3) * 8192 + (h * 64 + w * 8) * 64;
    gl_lds16(Bb + (size_t)(h * 64 + w * 8 + sr8) * DMODEL + kt * 64 + sc, dst);
  };

  // prologue: tiles 0 and 1 staged (4 loads each); wait only for tile 0
  stageA(0, 0); stageA(0, 1); stageB(0, 0); stageB(0, 1);
  stageA(1, 0); stageA(1, 1); stageB(1, 0); stageB(1, 1);
  asm volatile("s_waitcnt vmcnt(4)" ::: "memory");
  __builtin_amdgcn_s_barrier();
  asm volatile("" ::: "memory");

  for (int t = 0; t < 16; ++t) {
    const bool pre = (t + 2 < 16);
    if (pre) { stageA(t + 2, 0); stageA(t + 2, 1); stageB(t + 2, 0); stageB(t + 2, 1); }

    const ushort_t* As_ = smem + (t % 3) * 8192;
    const ushort_t* Bs_ = smem + 24576 + (t % 3) * 8192;

#pragma unroll
    for (int kk = 0; kk < 64; kk += 32) {
      const int cblk = (kk >> 3) + quad;
      bf16x8 af[2], bfr[4];
#pragma unroll
      for (int m = 0; m < 2; ++m)
        af[m] = *(const bf16x8*)(As_ + (wm * 32 + m * 16 + col) * 64 +
                                 ((cblk ^ csw) * 8));
#pragma unroll
      for (int n = 0; n < 4; ++n)
        bfr[n] = *(const bf16x8*)(Bs_ + (wn * 64 + n * 16 + col) * 64 +
                                  ((cblk ^ csw) * 8));
      __builtin_amdgcn_s_setprio(1);
#pragma unroll
      for (int m = 0; m < 2; ++m)
#pragma unroll
        for (int n = 0; n < 4; ++n)
          acc[m][n] = __builtin_amdgcn_mfma_f32_16x16x32_bf16(
              af[m], bfr[n], acc[m][n], 0, 0, 0);
      __builtin_amdgcn_s_setprio(0);
    }

    // counted wait: drain all but the 4 loads just issued (tile t+2)
    if (pre) asm volatile("s_waitcnt vmcnt(4)" ::: "memory");
    else     asm volatile("s_waitcnt vmcnt(0)" ::: "memory");
    __builtin_amdgcn_s_barrier();
    asm volatile("" ::: "memory");
  }

  // epilogue: fp32 C row-major (same fragment mapping as before)
#pragma unroll
  for (int m = 0; m < 2; ++m) {
    const int i = i0 + wm * 32 + m * 16 + quad * 4;
#pragma unroll
    for (int n = 0; n < 4; ++n) {
      const int j = j0 + wn * 64 + n * 16 + col;
#pragma unroll
      for (int r = 0; r < 4; ++r)
        C[(size_t)(i + r) * DMODEL + j] = acc[m][n][r];
    }
  }
}

// ---------------------------------------------------------------------------
// MFMA flash attention v12 + T5 setprio (best measured: 59.0 us). Unchanged.
// 3 LDS buffers per parity group, prefetch distance 2, counted vmcnt(2) +
// raw s_barrier per tile. 1024 thr, 16 waves = 4 q-units x 2 key-halves x
// 2 kt-parity groups. LDS 136 KiB; Obuf aliases staging.
// ---------------------------------------------------------------------------
__global__ __launch_bounds__(1024, 4)
void attn_mfma(const ushort_t* __restrict__ Qh, const ushort_t* __restrict__ Kh,
               const ushort_t* __restrict__ Vt, ushort_t* __restrict__ Om) {
  const int h   = blockIdx.x;
  const int g   = blockIdx.y;    // 0..15
  const int tid = threadIdx.x;
  const int w     = tid >> 6;      // 0..15
  const int wl    = w & 3;         // q-unit slot (32 q rows each)
  const int half  = (w >> 2) & 1;  // keys [0,32) or [32,64) of each tile
  const int ktpar = w >> 3;        // 0 = even tiles, 1 = odd tiles
  const int wg    = w & 7;         // staging wave index within parity group
  const int lane = tid & 63;
  const int quad = lane >> 4;
  const int col  = lane & 15;
  const int csw  = col & 7;      // row-derived swizzle key for reads

  __shared__ __align__(16) char smem[139264];
  ushort_t* Ks   = (ushort_t*)smem;                  // [6][64*64], swizzled
  ushort_t* Vs   = (ushort_t*)(smem + 49152);        // [6][64*64], swizzled
  ushort_t* Ps   = (ushort_t*)(smem + 98304);        // [16][32*PSTRIDE]
  float*    Obuf = (float*)smem;
  __shared__ float lbuf[3][4][2][16];
  ushort_t* psw = Ps + w * (32 * PSTRIDE);

  const int srow = wg * 8 + (lane >> 3);
  const int scol = (((lane & 7) ^ ((lane >> 3) & 7)) * 8);

  for (int pass = 0; pass < 2; ++pass) {
    const int qb      = pass ? (31 - g) : g;
    const int qbase   = qb * 128 + wl * 32;
    const int nkt_max = 2 * qb + 2;   // uniform across all waves, always even
    const int nt2     = nkt_max >> 1; // tiles per parity group

    // Q B-frags (pre-scaled by C2), resident for the key loop
    bf16x8 qf[2][2];
#pragma unroll
    for (int nq = 0; nq < 2; ++nq)
#pragma unroll
      for (int c = 0; c < 2; ++c)
        qf[nq][c] = *(const bf16x8*)(Qh +
            ((size_t)(h * LSEQ + qbase + nq * 16 + col)) * DHEAD + quad * 8 + c * 32);

    floatx4 ot[4][2];
#pragma unroll
    for (int md = 0; md < 4; ++md)
#pragma unroll
      for (int nq = 0; nq < 2; ++nq) ot[md][nq] = (floatx4){0.f, 0.f, 0.f, 0.f};
    float l_[2] = {0.f, 0.f};

    // stage tile kt into this parity group's LDS buffer b (0..2)
    auto stage = [&](int kt, int b) {
      const int key0 = kt * 64;
      const int boff = (ktpar * 3 + b) * 4096;
      gl_lds16(Kh + ((size_t)(h * LSEQ + key0 + srow)) * DHEAD + scol,
               Ks + boff + wg * 512);
      gl_lds16(Vt + ((size_t)(h * DHEAD + srow)) * LSEQ + key0 + scol,
               Vs + boff + wg * 512);
    };

    // prologue: stage iterations 0 and (if any) 1; wait only for iter 0
    stage(ktpar, 0);
    if (nt2 > 1) {
      stage(ktpar + 2, 1);
      asm volatile("s_waitcnt vmcnt(2)" ::: "memory");
    } else {
      asm volatile("s_waitcnt vmcnt(0)" ::: "memory");
    }
    __builtin_amdgcn_s_barrier();
    asm volatile("" ::: "memory");

    int bufn = 0;  // = ktt % 3
    for (int ktt = 0; ktt < nt2; ++ktt) {
      const int kt  = 2 * ktt + ktpar;
      const bool pre = (ktt + 2 < nt2);
      if (pre) {
        const int nb = (bufn >= 1) ? bufn - 1 : 2;  // (ktt+2) % 3
        stage(kt + 4, nb);
      }

      const ushort_t* kb = Ks + (ktpar * 3 + bufn) * 4096;
      const ushort_t* vb = Vs + (ktpar * 3 + bufn) * 4096;

      // kf frags from LDS (swizzled): row rk = half*32+mk*16+col, rk&7 = csw
      bf16x8 kf[2][2];
#pragma unroll
      for (int mk = 0; mk < 2; ++mk)
#pragma unroll
        for (int c = 0; c < 2; ++c)
          kf[mk][c] = *(const bf16x8*)(kb + (half * 32 + mk * 16 + col) * 64 +
                                       (((c * 4 + quad) ^ csw) * 8));

      // S^T = K . (C2*Q)^T  (32 keys x 32 q)
      floatx4 st[2][2];
#pragma unroll
      for (int mk = 0; mk < 2; ++mk)
#pragma unroll
        for (int nq = 0; nq < 2; ++nq) st[mk][nq] = (floatx4){0.f, 0.f, 0.f, 0.f};
      __builtin_amdgcn_s_setprio(1);
#pragma unroll
      for (int mk = 0; mk < 2; ++mk)
#pragma unroll
        for (int c = 0; c < 2; ++c)
#pragma unroll
          for (int nq = 0; nq < 2; ++nq)
            st[mk][nq] = __builtin_amdgcn_mfma_f32_16x16x32_bf16(
                kf[mk][c], qf[nq][c], st[mk][nq], 0, 0, 0);
      __builtin_amdgcn_s_setprio(0);

      // mask near/beyond the diagonal
      if (kt >= nkt_max - 2) {
        const int key0 = kt * 64 + half * 32;
#pragma unroll
        for (int mk = 0; mk < 2; ++mk) {
          const int keyb = key0 + mk * 16 + quad * 4;
#pragma unroll
          for (int nq = 0; nq < 2; ++nq) {
            const int q = qbase + nq * 16 + col;
#pragma unroll
            for (int r = 0; r < 4; ++r)
              if (keyb + r > q) st[mk][nq][r] = MASKV;
          }
        }
      }

      // p = exp2(S); accumulate l per-lane
#pragma unroll
      for (int mk = 0; mk < 2; ++mk)
#pragma unroll
        for (int nq = 0; nq < 2; ++nq) {
#pragma unroll
          for (int r = 0; r < 4; ++r) st[mk][nq][r] = EXP2F(st[mk][nq][r]);
          l_[nq] += (st[mk][nq][0] + st[mk][nq][1]) + (st[mk][nq][2] + st[mk][nq][3]);
        }

      // P^T -> per-wave LDS (truncating pack), then P B-frags
#pragma unroll
      for (int mk = 0; mk < 2; ++mk)
#pragma unroll
        for (int nq = 0; nq < 2; ++nq) {
          uint2 pk;
          pk.x = bfpack_trunc(st[mk][nq][0], st[mk][nq][1]);
          pk.y = bfpack_trunc(st[mk][nq][2], st[mk][nq][3]);
          *(uint2*)(psw + (nq * 16 + col) * PSTRIDE + mk * 16 + quad * 4) = pk;
        }
      bf16x8 pf[2];
#pragma unroll
      for (int nq = 0; nq < 2; ++nq)
        pf[nq] = *(const bf16x8*)(psw + (nq * 16 + col) * PSTRIDE + quad * 8);

      // vf frags from LDS (swizzled): row rv = md*16+col, rv&7 = csw
      bf16x8 vf[4];
#pragma unroll
      for (int md = 0; md < 4; ++md)
        vf[md] = *(const bf16x8*)(vb + (md * 16 + col) * 64 +
                                  (((half * 4 + quad) ^ csw) * 8));
      __builtin_amdgcn_s_setprio(1);
#pragma unroll
      for (int md = 0; md < 4; ++md)
#pragma unroll
        for (int nq = 0; nq < 2; ++nq)
          ot[md][nq] = __builtin_amdgcn_mfma_f32_16x16x32_bf16(
              vf[md], pf[nq], ot[md][nq], 0, 0, 0);
      __builtin_amdgcn_s_setprio(0);

      // counted wait: drain everything except the stage just issued
      if (pre) asm volatile("s_waitcnt vmcnt(2)" ::: "memory");
      else     asm volatile("s_waitcnt vmcnt(0)" ::: "memory");
      __builtin_amdgcn_s_barrier();
      asm volatile("" ::: "memory");
      bufn = (bufn == 2) ? 0 : bufn + 1;
    }

    // one-time l reduction per pass
    float lr[2];
#pragma unroll
    for (int nq = 0; nq < 2; ++nq) {
      float ls = l_[nq];
      ls += __shfl_xor(ls, 16);
      ls += __shfl_xor(ls, 32);
      lr[nq] = ls;
    }

    // 3 non-merger groups dump partials (Obuf aliases staging); merger is
    // group (half=0, ktpar=0).
    const int di = ((half << 1) | ktpar) - 1;  // -1 merger, else 0..2
    if (di >= 0) {
#pragma unroll
      for (int nq = 0; nq < 2; ++nq) {
        if (quad == 0) lbuf[di][wl][nq][col] = lr[nq];
#pragma unroll
        for (int md = 0; md < 4; ++md)
          *(float4*)(Obuf + di * 8704 + ((wl * 2 + nq) * 16 + col) * 68 + md * 16 + quad * 4) =
              (float4){ot[md][nq][0], ot[md][nq][1], ot[md][nq][2], ot[md][nq][3]};
      }
    }
    __syncthreads();

    if (di < 0) {  // merger group sums 4 partials and writes Om
#pragma unroll
      for (int nq = 0; nq < 2; ++nq) {
        const float inv = 1.0f / (lr[nq] + lbuf[0][wl][nq][col] +
                                  lbuf[1][wl][nq][col] + lbuf[2][wl][nq][col]);
        const int q = qbase + nq * 16 + col;
#pragma unroll
        for (int md = 0; md < 4; ++md) {
          const int ob_off = ((wl * 2 + nq) * 16 + col) * 68 + md * 16 + quad * 4;
          const float4 o0 = *(const float4*)(Obuf + ob_off);
          const float4 o1 = *(const float4*)(Obuf + 8704 + ob_off);
          const float4 o2 = *(const float4*)(Obuf + 17408 + ob_off);
          uint2 pk;
          pk.x = bf16pair((ot[md][nq][0] + o0.x + o1.x + o2.x) * inv,
                          (ot[md][nq][1] + o0.y + o1.y + o2.y) * inv);
          pk.y = bf16pair((ot[md][nq][2] + o0.z + o1.z + o2.z) * inv,
                          (ot[md][nq][3] + o0.w + o1.w + o2.w) * inv);
          *(uint2*)(Om + (size_t)q * DMODEL + h * DHEAD + md * 16 + quad * 4) = pk;
        }
      }
    }
    __syncthreads();  // Obuf reads done before next pass re-stages over it
  }
}

extern "C" void kernel_launch(void* const* d_in, const int* in_sizes, int n_in,
                              void* d_out, int out_size, void* d_ws, size_t ws_size,
                              hipStream_t stream) {
  const float* x  = (const float*)d_in[0];
  const float* Wq = (const float*)d_in[2];
  const float* Wk = (const float*)d_in[3];
  const float* Wv = (const float*)d_in[4];
  const float* Wo = (const float*)d_in[5];
  float* out = (float*)d_out;

  const size_t M1 = (size_t)1 << 20;
  ushort_t* xb  = (ushort_t*)d_ws;      // bf16 x          4M elems
  ushort_t* Wb  = xb  + 4 * M1;         // bf16 Wq|Wk|Wv   3M (contiguous)
  ushort_t* wob = Wb  + 3 * M1;         // bf16 Wo         1M
  ushort_t* Qh  = wob + 1 * M1;         // bf16 [H][L][DH] 4M (pre-scaled C2)
  ushort_t* Kh  = Qh  + 4 * M1;         // bf16 [H][L][DH] 4M
  ushort_t* Vt  = Kh  + 4 * M1;         // bf16 [H][DH][L] 4M
  ushort_t* Om  = Vt  + 4 * M1;         // bf16 [L][D]     4M
  float2*   rope = (float2*)(Om + 4 * M1);  // 4096x32 float2, 1 MB

  prep_fused<<<8704, 256, 0, stream>>>(x, Wq, Wk, Wv, Wo, xb, rope);
  gemm256_qkv<<<256, 512, 0, stream>>>(Wb, xb, rope, Qh, Kh, Vt);
  attn_mfma<<<dim3(NH, 16), 1024, 0, stream>>>(Qh, Kh, Vt, Om);
  gemm_out<<<256, 512, 0, stream>>>(Om, wob, out);
}